// Round 5
// baseline (119.470 us; speedup 1.0000x reference)
//
#include <hip/hip_runtime.h>
#include <hip/hip_bf16.h>
#include <stdint.h>

typedef __attribute__((ext_vector_type(8))) short bf16x8;
typedef __attribute__((ext_vector_type(4))) float f32x4;
typedef __attribute__((ext_vector_type(4))) unsigned int u32x4;

__device__ __forceinline__ float u2f(unsigned int u) {
  union { unsigned int i; float f; } c; c.i = u; return c.f;
}
__device__ __forceinline__ unsigned int f2b(float f) {
  union { float f; unsigned int i; } c; c.f = f;
  unsigned int x = c.i;
  return (x + 0x7fffu + ((x >> 16) & 1u)) >> 16;  // RNE to bf16
}

// ================= prep kernel =================
// blocks 0..575    : offset conv + 32B sample-descriptor build (b,g,kk) x 4 bands
// blocks 576..1599 : transpose x (B,C,H,W) f32 -> xt (B,H,W,C) bf16
// blocks 1600..1855: weight pack -> chunk-major linear rows (A read direct to regs)
__global__ __launch_bounds__(256) void k_prep(
    const float* __restrict__ shape, const float* __restrict__ w_off,
    const float* __restrict__ x, const float* __restrict__ wd,
    char* __restrict__ desc, unsigned short* __restrict__ xt,
    unsigned short* __restrict__ wp) {
  __shared__ float tile[64][65];
  int bid = blockIdx.x;
  int t = threadIdx.x;
  if (bid < 576) {
    // ---- descriptors: {u32 off[4] (byte offsets into xt image, g folded), u32 w01, u32 w23, pad} ----
    int band = bid & 3;
    int rem = bid >> 2;                 // = b*36 + g*9 + kk
    int b = rem / 36, r2 = rem % 36, g = r2 / 9, kk = r2 % 9;
    int ky = kk / 3, kx = kk - ky * 3;
    int ocy = g * 18 + kk * 2;
    float wy[18], wx[18];
#pragma unroll
    for (int i = 0; i < 18; ++i) { wy[i] = w_off[ocy * 18 + i]; wx[i] = w_off[(ocy + 1) * 18 + i]; }
    const float* sp = shape + (size_t)b * 2 * 4096;
    char* dp = desc + (size_t)rem * 4096 * 32;
#pragma unroll
    for (int e = 0; e < 4; ++e) {
      int p = band * 1024 + t * 4 + e;
      int y = p >> 6, xx0 = p & 63;
      float dy = 0.f, dx = 0.f;
#pragma unroll
      for (int ic = 0; ic < 2; ++ic)
#pragma unroll
        for (int kyy = 0; kyy < 3; ++kyy) {
          int yy = y + kyy - 1;
          if (yy < 0 || yy > 63) continue;
#pragma unroll
          for (int kxx = 0; kxx < 3; ++kxx) {
            int xx = xx0 + kxx - 1;
            if (xx < 0 || xx > 63) continue;
            float sv = sp[ic * 4096 + yy * 64 + xx];
            dy += sv * wy[ic * 9 + kyy * 3 + kxx];
            dx += sv * wx[ic * 9 + kyy * 3 + kxx];
          }
        }
      float sy = dy + (float)(y + ky - 1);
      float sx = dx + (float)(xx0 + kx - 1);
      float fy = floorf(sy), fx = floorf(sx);
      float ly = sy - fy, lx = sx - fx;
      int y0 = (int)fy, x0 = (int)fx;
      float vy0 = (y0 >= 0 && y0 <= 63) ? 1.f : 0.f;
      float vy1 = (y0 >= -1 && y0 <= 62) ? 1.f : 0.f;
      float vx0 = (x0 >= 0 && x0 <= 63) ? 1.f : 0.f;
      float vx1 = (x0 >= -1 && x0 <= 62) ? 1.f : 0.f;
      float w00 = (1.f - ly) * (1.f - lx) * vy0 * vx0;
      float w01 = (1.f - ly) * lx * vy0 * vx1;
      float w10 = ly * (1.f - lx) * vy1 * vx0;
      float w11 = ly * lx * vy1 * vx1;
      unsigned int yc0 = (unsigned int)min(max(y0, 0), 63);
      unsigned int yc1 = (unsigned int)min(max(y0 + 1, 0), 63);
      unsigned int xc0 = (unsigned int)min(max(x0, 0), 63);
      unsigned int xc1 = (unsigned int)min(max(x0 + 1, 0), 63);
      unsigned int gb = (unsigned int)(g * 128);
      u32x4 offs;
      offs[0] = (yc0 * 64 + xc0) * 512 + gb;
      offs[1] = (yc0 * 64 + xc1) * 512 + gb;
      offs[2] = (yc1 * 64 + xc0) * 512 + gb;
      offs[3] = (yc1 * 64 + xc1) * 512 + gb;
      uint2 wpk;
      wpk.x = f2b(w00) | (f2b(w01) << 16);
      wpk.y = f2b(w10) | (f2b(w11) << 16);
      char* r = dp + (size_t)p * 32;
      *(u32x4*)(r) = offs;
      *(uint2*)(r + 16) = wpk;
    }
  } else if (bid < 1600) {
    // ---- transpose ----
    int id = bid - 576;
    int b = id >> 8, ct = (id >> 6) & 3, pt = id & 63;
    int c0 = ct * 64, p0 = pt * 64;
#pragma unroll
    for (int i = 0; i < 4; ++i) {
      int row = (t >> 4) + i * 16;
      int seg = t & 15;
      float4 v = *(const float4*)&x[(size_t)(b * 256 + c0 + row) * 4096 + p0 + seg * 4];
      tile[row][seg * 4 + 0] = v.x;
      tile[row][seg * 4 + 1] = v.y;
      tile[row][seg * 4 + 2] = v.z;
      tile[row][seg * 4 + 3] = v.w;
    }
    __syncthreads();
    {
      int pl = t >> 2;
      int cs = (t & 3) * 16;
      unsigned int wbuf[8];
#pragma unroll
      for (int j = 0; j < 8; ++j)
        wbuf[j] = f2b(tile[cs + 2 * j][pl]) | (f2b(tile[cs + 2 * j + 1][pl]) << 16);
      unsigned short* dst = xt + (size_t)(b * 4096 + p0 + pl) * 256 + c0 + cs;
      *(u32x4*)(dst) = *(u32x4*)&wbuf[0];
      *(u32x4*)(dst + 8) = *(u32x4*)&wbuf[4];
    }
  } else {
    // ---- weight pack: wp[chunk=kk*4+g][m][c] = wd[m][g*64+c][kk] (linear rows) ----
    int id = (bid - 1600) * 256 + t;
    int m = id >> 8, ci = id & 255;
    int g = ci >> 6, c = ci & 63;
    const float* src = wd + (size_t)(m * 256 + ci) * 9;
    float v[9];
#pragma unroll
    for (int kk = 0; kk < 9; ++kk) v[kk] = src[kk];
#pragma unroll
    for (int kk = 0; kk < 9; ++kk)
      wp[(size_t)(kk * 4 + g) * 16384 + m * 64 + c] = (unsigned short)f2b(v[kk]);
  }
}

// ================= main fused kernel =================
// grid 256: (b, y); tile M=256 x N=64, 1024 threads (16 waves, wave-tile 32x32)
// A: direct global->VGPR fragments (dbuf 1 phase ahead). B: LDS dbuf 2x8KB.
// Barrier per phase = lgkmcnt(0) + s_barrier only; all vmem flies across.
struct CSet { uint2 v0, v1, v2, v3; uint2 w; };

#define DESC_LD(c, dvo, dvw) do { \
    const char* rp_ = descb + (size_t)((((c) & 3) * 9 + ((c) >> 2))) * (4096 * 32); \
    dvo = *(const u32x4*)(rp_); \
    dvw = *(const uint2*)(rp_ + 16); \
  } while (0)

#define CORNERS(S, dvo, dvw) do { \
    (S).v0 = *(const uint2*)(xtbB + (dvo)[0] + cb16); \
    (S).v1 = *(const uint2*)(xtbB + (dvo)[1] + cb16); \
    (S).v2 = *(const uint2*)(xtbB + (dvo)[2] + cb16); \
    (S).v3 = *(const uint2*)(xtbB + (dvo)[3] + cb16); \
    (S).w = (dvw); \
  } while (0)

#define BLEND(S, bbuf) do { \
    float w0_ = u2f((S).w.x << 16), w1_ = u2f((S).w.x & 0xffff0000u); \
    float w2_ = u2f((S).w.y << 16), w3_ = u2f((S).w.y & 0xffff0000u); \
    float lo0 = 0.f, hi0 = 0.f, lo1 = 0.f, hi1 = 0.f; \
    lo0 += w0_ * u2f((S).v0.x << 16); hi0 += w0_ * u2f((S).v0.x & 0xffff0000u); \
    lo1 += w0_ * u2f((S).v0.y << 16); hi1 += w0_ * u2f((S).v0.y & 0xffff0000u); \
    lo0 += w1_ * u2f((S).v1.x << 16); hi0 += w1_ * u2f((S).v1.x & 0xffff0000u); \
    lo1 += w1_ * u2f((S).v1.y << 16); hi1 += w1_ * u2f((S).v1.y & 0xffff0000u); \
    lo0 += w2_ * u2f((S).v2.x << 16); hi0 += w2_ * u2f((S).v2.x & 0xffff0000u); \
    lo1 += w2_ * u2f((S).v2.y << 16); hi1 += w2_ * u2f((S).v2.y & 0xffff0000u); \
    lo0 += w3_ * u2f((S).v3.x << 16); hi0 += w3_ * u2f((S).v3.x & 0xffff0000u); \
    lo1 += w3_ * u2f((S).v3.y << 16); hi1 += w3_ * u2f((S).v3.y & 0xffff0000u); \
    uint2 o_; \
    o_.x = f2b(lo0) | (f2b(hi0) << 16); \
    o_.y = f2b(lo1) | (f2b(hi1) << 16); \
    *(uint2*)((bbuf) + bwr) = o_; \
  } while (0)

#define LOAD_A(c, F) do { \
    const unsigned short* ap_ = wpl + (size_t)(c) * 16384; \
    F##0 = *(const bf16x8*)(ap_); \
    F##1 = *(const bf16x8*)(ap_ + 1024); \
    F##2 = *(const bf16x8*)(ap_ + 32); \
    F##3 = *(const bf16x8*)(ap_ + 1056); \
  } while (0)

#define MFMA4(F, bbuf) do { \
    bf16x8 b00_ = *(const bf16x8*)((bbuf) + brow0 + (kq ^ swz)); \
    bf16x8 b10_ = *(const bf16x8*)((bbuf) + brow1 + (kq ^ swz)); \
    acc00 = __builtin_amdgcn_mfma_f32_16x16x32_bf16(F##0, b00_, acc00, 0, 0, 0); \
    acc01 = __builtin_amdgcn_mfma_f32_16x16x32_bf16(F##0, b10_, acc01, 0, 0, 0); \
    acc10 = __builtin_amdgcn_mfma_f32_16x16x32_bf16(F##1, b00_, acc10, 0, 0, 0); \
    acc11 = __builtin_amdgcn_mfma_f32_16x16x32_bf16(F##1, b10_, acc11, 0, 0, 0); \
    bf16x8 b01_ = *(const bf16x8*)((bbuf) + brow0 + ((64 + kq) ^ swz)); \
    bf16x8 b11_ = *(const bf16x8*)((bbuf) + brow1 + ((64 + kq) ^ swz)); \
    acc00 = __builtin_amdgcn_mfma_f32_16x16x32_bf16(F##2, b01_, acc00, 0, 0, 0); \
    acc01 = __builtin_amdgcn_mfma_f32_16x16x32_bf16(F##2, b11_, acc01, 0, 0, 0); \
    acc10 = __builtin_amdgcn_mfma_f32_16x16x32_bf16(F##3, b01_, acc10, 0, 0, 0); \
    acc11 = __builtin_amdgcn_mfma_f32_16x16x32_bf16(F##3, b11_, acc11, 0, 0, 0); \
  } while (0)

// Phase(c): load A(c+1)->next regs; issue corners(c+2); load desc(c+3);
// MFMA on A(c),B(c); blend corners(c+1)->B(c+1); lgkm drain; barrier.
#define PHASE(c, AF, AG, Bcur, Bnext, Sfill, Sblend, dvoF, dvwF, dvoU, dvwU) do { \
    int ca_ = (c) + 1 < 36 ? (c) + 1 : 35; \
    int cd_ = (c) + 3 < 36 ? (c) + 3 : 35; \
    LOAD_A(ca_, AG); \
    CORNERS(Sfill, dvoU, dvwU); \
    DESC_LD(cd_, dvoF, dvwF); \
    MFMA4(AF, Bcur); \
    BLEND(Sblend, Bnext); \
    asm volatile("s_waitcnt lgkmcnt(0)" ::: "memory"); \
    __builtin_amdgcn_s_barrier(); \
  } while (0)

__global__ __launch_bounds__(1024, 4) void k_deform_main(
    const unsigned short* __restrict__ xt, const unsigned short* __restrict__ wp,
    const char* __restrict__ desc, float* __restrict__ out) {
  __shared__ __align__(16) char lds[16384];  // B0, B1: 8KB each
  const int t = threadIdx.x;
  const int l = t & 63;
  const int wid = t >> 6;                    // 0..15
  const int wm = wid >> 1;                   // m-tile 0..7
  const int wn = wid & 1;                    // n-tile 0..1

  int orig = blockIdx.x;
  int bid = (orig & 7) * 32 + (orig >> 3);   // XCD chunked swizzle (256%8==0)
  const int b = bid >> 6;
  const int y = bid & 63;

  const int p = t >> 4;              // position 0..63
  const int cq = t & 15;             // channel quad
  const int cb16 = cq * 8;
  const int bwr = p * 128 + ((cq * 8) ^ ((p & 7) << 4));

  const int lm = l & 15;
  const int kq = (l >> 4) << 4;
  const int swz = (lm & 7) << 4;
  const int brow0 = (wn * 32 + lm) * 128;
  const int brow1 = brow0 + 2048;

  f32x4 acc00 = {}, acc01 = {}, acc10 = {}, acc11 = {};

  const char* descb = desc + (size_t)(b * 36 * 4096 + y * 64 + p) * 32;
  const char* xtbB = (const char*)(xt + (size_t)b * 4096 * 256);
  const unsigned short* wpl = wp + (wm * 32 + lm) * 64 + ((l >> 4) << 3);

  char* ldsB0 = lds;
  char* ldsB1 = lds + 8192;

  bf16x8 AFe0, AFe1, AFe2, AFe3, AFo0, AFo1, AFo2, AFo3;
  CSet SE, SO;
  u32x4 dvoE, dvoO;
  uint2 dvwE, dvwO;

  // ---- prologue: A(0) in regs-in-flight, B(0) built, corners(1) flying, desc(2) loaded ----
  {
    u32x4 o0, o1; uint2 w0p, w1p;
    DESC_LD(0, o0, w0p);
    DESC_LD(1, o1, w1p);
    DESC_LD(2, dvoO, dvwO);
    LOAD_A(0, AFe);
    CSet S0;
    CORNERS(S0, o0, w0p);
    CORNERS(SO, o1, w1p);
    BLEND(S0, ldsB0);
    asm volatile("s_waitcnt lgkmcnt(0)" ::: "memory");
    __builtin_amdgcn_s_barrier();
  }

  for (int pr = 0; pr < 18; ++pr) {
    const int c0 = pr * 2;
    PHASE(c0,     AFe, AFo, ldsB0, ldsB1, SE, SO, dvoE, dvwE, dvoO, dvwO);
    PHASE(c0 + 1, AFo, AFe, ldsB1, ldsB0, SO, SE, dvoO, dvwO, dvoE, dvwE);
  }

  // ---- epilogue: ReLU + fp32 store ----
  const int lm4 = (l >> 4) << 2;
  float* ob = out + (size_t)(b * 256 + wm * 32) * 4096 + y * 64 + wn * 32;
#pragma unroll
  for (int r = 0; r < 4; ++r) {
    ob[(size_t)(lm4 + r) * 4096 + lm] = fmaxf(acc00[r], 0.f);
    ob[(size_t)(lm4 + r) * 4096 + 16 + lm] = fmaxf(acc01[r], 0.f);
    ob[(size_t)(16 + lm4 + r) * 4096 + lm] = fmaxf(acc10[r], 0.f);
    ob[(size_t)(16 + lm4 + r) * 4096 + 16 + lm] = fmaxf(acc11[r], 0.f);
  }
}

extern "C" void kernel_launch(void* const* d_in, const int* in_sizes, int n_in,
                              void* d_out, int out_size, void* d_ws, size_t ws_size,
                              hipStream_t stream) {
  const float* x     = (const float*)d_in[0];
  const float* shape = (const float*)d_in[1];
  const float* w_off = (const float*)d_in[2];
  const float* w_def = (const float*)d_in[3];
  float* out = (float*)d_out;
  char* ws = (char*)d_ws;

  char* desc          = ws;                                           // 18,874,368 B
  unsigned short* xt  = (unsigned short*)(ws + 18874368);             //  8,388,608 B
  unsigned short* wpk = (unsigned short*)(ws + 18874368 + 8388608);   //  1,179,648 B

  k_prep<<<1856, 256, 0, stream>>>(shape, w_off, x, w_def, desc, xt, wpk);
  k_deform_main<<<256, 1024, 0, stream>>>(xt, wpk, desc, out);
}

// Round 6
// 106.476 us; speedup vs baseline: 1.1220x; 1.1220x over previous
//
#include <hip/hip_runtime.h>
#include <hip/hip_bf16.h>
#include <stdint.h>

typedef __attribute__((ext_vector_type(8))) short bf16x8;
typedef __attribute__((ext_vector_type(4))) float f32x4;
typedef __attribute__((ext_vector_type(4))) unsigned int u32x4;

__device__ __forceinline__ float u2f(unsigned int u) {
  union { unsigned int i; float f; } c; c.i = u; return c.f;
}
__device__ __forceinline__ unsigned int f2b(float f) {
  union { float f; unsigned int i; } c; c.f = f;
  unsigned int x = c.i;
  return (x + 0x7fffu + ((x >> 16) & 1u)) >> 16;  // RNE to bf16
}

// ================= prep kernel =================
// blocks 0..575    : offset conv + 16B sample-descriptor build (b,g,kk) x 4 bands
// blocks 576..1599 : transpose x (B,C,H,W) f32 -> xt (B,H,W,C) bf16
// blocks 1600..1855: weight pack -> chunk-major linear rows (A read direct to regs)
__global__ __launch_bounds__(256) void k_prep(
    const float* __restrict__ shape, const float* __restrict__ w_off,
    const float* __restrict__ x, const float* __restrict__ wd,
    char* __restrict__ desc, unsigned short* __restrict__ xt,
    unsigned short* __restrict__ wp) {
  __shared__ float tile[64][65];
  int bid = blockIdx.x;
  int t = threadIdx.x;
  if (bid < 576) {
    // ---- descriptors (16B): {u32 idx01 (two u16 pos idx), u32 idx23, u32 w01, u32 w23} ----
    int band = bid & 3;
    int rem = bid >> 2;                 // = b*36 + g*9 + kk
    int b = rem / 36, r2 = rem % 36, g = r2 / 9, kk = r2 % 9;
    int ky = kk / 3, kx = kk - ky * 3;
    int ocy = g * 18 + kk * 2;
    float wy[18], wx[18];
#pragma unroll
    for (int i = 0; i < 18; ++i) { wy[i] = w_off[ocy * 18 + i]; wx[i] = w_off[(ocy + 1) * 18 + i]; }
    const float* sp = shape + (size_t)b * 2 * 4096;
    char* dp = desc + (size_t)rem * 4096 * 16;
#pragma unroll
    for (int e = 0; e < 4; ++e) {
      int p = band * 1024 + t * 4 + e;
      int y = p >> 6, xx0 = p & 63;
      float dy = 0.f, dx = 0.f;
#pragma unroll
      for (int ic = 0; ic < 2; ++ic)
#pragma unroll
        for (int kyy = 0; kyy < 3; ++kyy) {
          int yy = y + kyy - 1;
          if (yy < 0 || yy > 63) continue;
#pragma unroll
          for (int kxx = 0; kxx < 3; ++kxx) {
            int xx = xx0 + kxx - 1;
            if (xx < 0 || xx > 63) continue;
            float sv = sp[ic * 4096 + yy * 64 + xx];
            dy += sv * wy[ic * 9 + kyy * 3 + kxx];
            dx += sv * wx[ic * 9 + kyy * 3 + kxx];
          }
        }
      float sy = dy + (float)(y + ky - 1);
      float sx = dx + (float)(xx0 + kx - 1);
      float fy = floorf(sy), fx = floorf(sx);
      float ly = sy - fy, lx = sx - fx;
      int y0 = (int)fy, x0 = (int)fx;
      float vy0 = (y0 >= 0 && y0 <= 63) ? 1.f : 0.f;
      float vy1 = (y0 >= -1 && y0 <= 62) ? 1.f : 0.f;
      float vx0 = (x0 >= 0 && x0 <= 63) ? 1.f : 0.f;
      float vx1 = (x0 >= -1 && x0 <= 62) ? 1.f : 0.f;
      float w00 = (1.f - ly) * (1.f - lx) * vy0 * vx0;
      float w01 = (1.f - ly) * lx * vy0 * vx1;
      float w10 = ly * (1.f - lx) * vy1 * vx0;
      float w11 = ly * lx * vy1 * vx1;
      unsigned int yc0 = (unsigned int)min(max(y0, 0), 63);
      unsigned int yc1 = (unsigned int)min(max(y0 + 1, 0), 63);
      unsigned int xc0 = (unsigned int)min(max(x0, 0), 63);
      unsigned int xc1 = (unsigned int)min(max(x0 + 1, 0), 63);
      u32x4 d;
      d[0] = (yc0 * 64 + xc0) | ((yc0 * 64 + xc1) << 16);
      d[1] = (yc1 * 64 + xc0) | ((yc1 * 64 + xc1) << 16);
      d[2] = f2b(w00) | (f2b(w01) << 16);
      d[3] = f2b(w10) | (f2b(w11) << 16);
      *(u32x4*)(dp + (size_t)p * 16) = d;
    }
  } else if (bid < 1600) {
    // ---- transpose ----
    int id = bid - 576;
    int b = id >> 8, ct = (id >> 6) & 3, pt = id & 63;
    int c0 = ct * 64, p0 = pt * 64;
#pragma unroll
    for (int i = 0; i < 4; ++i) {
      int row = (t >> 4) + i * 16;
      int seg = t & 15;
      float4 v = *(const float4*)&x[(size_t)(b * 256 + c0 + row) * 4096 + p0 + seg * 4];
      tile[row][seg * 4 + 0] = v.x;
      tile[row][seg * 4 + 1] = v.y;
      tile[row][seg * 4 + 2] = v.z;
      tile[row][seg * 4 + 3] = v.w;
    }
    __syncthreads();
    {
      int pl = t >> 2;
      int cs = (t & 3) * 16;
      unsigned int wbuf[8];
#pragma unroll
      for (int j = 0; j < 8; ++j)
        wbuf[j] = f2b(tile[cs + 2 * j][pl]) | (f2b(tile[cs + 2 * j + 1][pl]) << 16);
      unsigned short* dst = xt + (size_t)(b * 4096 + p0 + pl) * 256 + c0 + cs;
      *(u32x4*)(dst) = *(u32x4*)&wbuf[0];
      *(u32x4*)(dst + 8) = *(u32x4*)&wbuf[4];
    }
  } else {
    // ---- weight pack: wp[chunk=kk*4+g][m][c] = wd[m][g*64+c][kk] (linear rows) ----
    int id = (bid - 1600) * 256 + t;
    int m = id >> 8, ci = id & 255;
    int g = ci >> 6, c = ci & 63;
    const float* src = wd + (size_t)(m * 256 + ci) * 9;
    float v[9];
#pragma unroll
    for (int kk = 0; kk < 9; ++kk) v[kk] = src[kk];
#pragma unroll
    for (int kk = 0; kk < 9; ++kk)
      wp[(size_t)(kk * 4 + g) * 16384 + m * 64 + c] = (unsigned short)f2b(v[kk]);
  }
}

// ================= main fused kernel =================
// grid 512: (b, y, xh); tile M=256 x N=32, 512 threads (8 waves), 2 blocks/CU.
// A: global->VGPR dbuf. B: LDS dbuf 2x4KB (only LDS). Barriers: lgkmcnt(0)+s_barrier only.
// Pipeline: corners issued 3 phases before blend; desc 3 phases before corner-issue.
struct CSet { uint2 v0, v1, v2, v3; unsigned int w01, w23; };

#define DESC_LD(c, dv) do { \
    dv = *(const u32x4*)(descb + (size_t)(((c) & 3) * 9 + ((c) >> 2)) * 65536); \
  } while (0)

#define CORNERS(S, dv, cc) do { \
    unsigned int base_ = (unsigned int)(((cc) & 3) << 7) + cb16; \
    (S).v0 = *(const uint2*)(xtbB + (((dv)[0] & 0xffffu) << 9) + base_); \
    (S).v1 = *(const uint2*)(xtbB + (((dv)[0] >> 16) << 9) + base_); \
    (S).v2 = *(const uint2*)(xtbB + (((dv)[1] & 0xffffu) << 9) + base_); \
    (S).v3 = *(const uint2*)(xtbB + (((dv)[1] >> 16) << 9) + base_); \
    (S).w01 = (dv)[2]; \
    (S).w23 = (dv)[3]; \
  } while (0)

#define BLEND(S, bbuf) do { \
    float w0_ = u2f((S).w01 << 16), w1_ = u2f((S).w01 & 0xffff0000u); \
    float w2_ = u2f((S).w23 << 16), w3_ = u2f((S).w23 & 0xffff0000u); \
    float lo0 = 0.f, hi0 = 0.f, lo1 = 0.f, hi1 = 0.f; \
    lo0 += w0_ * u2f((S).v0.x << 16); hi0 += w0_ * u2f((S).v0.x & 0xffff0000u); \
    lo1 += w0_ * u2f((S).v0.y << 16); hi1 += w0_ * u2f((S).v0.y & 0xffff0000u); \
    lo0 += w1_ * u2f((S).v1.x << 16); hi0 += w1_ * u2f((S).v1.x & 0xffff0000u); \
    lo1 += w1_ * u2f((S).v1.y << 16); hi1 += w1_ * u2f((S).v1.y & 0xffff0000u); \
    lo0 += w2_ * u2f((S).v2.x << 16); hi0 += w2_ * u2f((S).v2.x & 0xffff0000u); \
    lo1 += w2_ * u2f((S).v2.y << 16); hi1 += w2_ * u2f((S).v2.y & 0xffff0000u); \
    lo0 += w3_ * u2f((S).v3.x << 16); hi0 += w3_ * u2f((S).v3.x & 0xffff0000u); \
    lo1 += w3_ * u2f((S).v3.y << 16); hi1 += w3_ * u2f((S).v3.y & 0xffff0000u); \
    uint2 o_; \
    o_.x = f2b(lo0) | (f2b(hi0) << 16); \
    o_.y = f2b(lo1) | (f2b(hi1) << 16); \
    *(uint2*)((bbuf) + bwr) = o_; \
  } while (0)

#define LOAD_A(c, F) do { \
    const unsigned short* ap_ = wpl + (size_t)(c) * 16384; \
    F##0 = *(const bf16x8*)(ap_); \
    F##1 = *(const bf16x8*)(ap_ + 1024); \
    F##2 = *(const bf16x8*)(ap_ + 32); \
    F##3 = *(const bf16x8*)(ap_ + 1056); \
  } while (0)

#define MFMA4(F, bbuf) do { \
    bf16x8 b0_ = *(const bf16x8*)((bbuf) + brow0 + (kq ^ swz)); \
    bf16x8 b1_ = *(const bf16x8*)((bbuf) + brow1 + (kq ^ swz)); \
    acc00 = __builtin_amdgcn_mfma_f32_16x16x32_bf16(F##0, b0_, acc00, 0, 0, 0); \
    acc01 = __builtin_amdgcn_mfma_f32_16x16x32_bf16(F##0, b1_, acc01, 0, 0, 0); \
    acc10 = __builtin_amdgcn_mfma_f32_16x16x32_bf16(F##1, b0_, acc10, 0, 0, 0); \
    acc11 = __builtin_amdgcn_mfma_f32_16x16x32_bf16(F##1, b1_, acc11, 0, 0, 0); \
    bf16x8 b2_ = *(const bf16x8*)((bbuf) + brow0 + ((64 + kq) ^ swz)); \
    bf16x8 b3_ = *(const bf16x8*)((bbuf) + brow1 + ((64 + kq) ^ swz)); \
    acc00 = __builtin_amdgcn_mfma_f32_16x16x32_bf16(F##2, b2_, acc00, 0, 0, 0); \
    acc01 = __builtin_amdgcn_mfma_f32_16x16x32_bf16(F##2, b3_, acc01, 0, 0, 0); \
    acc10 = __builtin_amdgcn_mfma_f32_16x16x32_bf16(F##3, b2_, acc10, 0, 0, 0); \
    acc11 = __builtin_amdgcn_mfma_f32_16x16x32_bf16(F##3, b3_, acc11, 0, 0, 0); \
  } while (0)

#define BAR() do { \
    asm volatile("s_waitcnt lgkmcnt(0)" ::: "memory"); \
    __builtin_amdgcn_s_barrier(); \
  } while (0)

// Phase(c): issue A(c+1); issue corners(c+3) [desc slot c%3]; load desc(c+5) [slot (c+2)%3];
// blend corners(c+1) [slot (c+1)%3] -> B[(c+1)&1]; MFMA A(c) x B[c&1]; barrier.
#define PHASE(c, Fcur, Fnext, Sfill, Sblend, dvUse, dvFill, Bcur, Bnext) do { \
    LOAD_A((c) + 1, Fnext); \
    CORNERS(Sfill, dvUse, (c) + 3); \
    DESC_LD((c) + 5, dvFill); \
    BLEND(Sblend, Bnext); \
    MFMA4(Fcur, Bcur); \
    BAR(); \
  } while (0)

__global__ __launch_bounds__(512, 4) void k_deform_main(
    const unsigned short* __restrict__ xt, const unsigned short* __restrict__ wp,
    const char* __restrict__ desc, float* __restrict__ out) {
  __shared__ __align__(16) char lds[8192];  // B0, B1: 4KB each
  const int t = threadIdx.x;
  const int l = t & 63;
  const int wid = t >> 6;                    // 0..7 (m-slice)

  int orig = blockIdx.x;
  int bid = (orig & 7) * 64 + (orig >> 3);   // XCD chunked swizzle (512%8==0)
  const int xh = bid & 1;
  const int rowid = bid >> 1;
  const int b = rowid >> 6;
  const int y = rowid & 63;

  const int p = t >> 4;              // local position 0..31
  const int cq = t & 15;             // channel quad
  const int xg = xh * 32 + p;
  const unsigned int cb16 = cq * 8;
  const int bwr = p * 128 + ((cq * 8) ^ ((p & 7) << 4));

  const int lm = l & 15;
  const int kq = (l >> 4) << 4;
  const int swz = (lm & 7) << 4;
  const int brow0 = lm * 128;
  const int brow1 = brow0 + 2048;

  f32x4 acc00 = {}, acc01 = {}, acc10 = {}, acc11 = {};

  const char* descb = desc + (size_t)(b * 36 * 4096 + y * 64 + xg) * 16;
  const char* xtbB = (const char*)(xt + (size_t)b * 4096 * 256);
  const unsigned short* wpl = wp + (wid * 32 + lm) * 64 + ((l >> 4) << 3);

  char* ldsB0 = lds;
  char* ldsB1 = lds + 4096;

  bf16x8 FA0, FA1, FA2, FA3, FB0, FB1, FB2, FB3;
  CSet S0, S1, S2;
  u32x4 dvA, dvB, dvC;

  // ---- prologue: A(0)->FA; corners 0,1,2 issued; desc 3,4 held; B(0) built ----
  {
    DESC_LD(0, dvA);
    DESC_LD(1, dvB);
    DESC_LD(2, dvC);
    LOAD_A(0, FA);
    CORNERS(S0, dvA, 0);
    CORNERS(S1, dvB, 1);
    CORNERS(S2, dvC, 2);
    DESC_LD(3, dvA);
    DESC_LD(4, dvB);
    BLEND(S0, ldsB0);
    BAR();
  }

  // ---- main loop: phases 0..29 (all pipeline indices in range, no guards) ----
  for (int pr = 0; pr < 5; ++pr) {
    const int c = pr * 6;
    PHASE(c + 0, FA, FB, S0, S1, dvA, dvC, ldsB0, ldsB1);
    PHASE(c + 1, FB, FA, S1, S2, dvB, dvA, ldsB1, ldsB0);
    PHASE(c + 2, FA, FB, S2, S0, dvC, dvB, ldsB0, ldsB1);
    PHASE(c + 3, FB, FA, S0, S1, dvA, dvC, ldsB1, ldsB0);
    PHASE(c + 4, FA, FB, S1, S2, dvB, dvA, ldsB0, ldsB1);
    PHASE(c + 5, FB, FA, S2, S0, dvC, dvB, ldsB1, ldsB0);
  }

  // ---- tail: phases 30..35, statically peeled ----
  // c=30 (k=0)
  LOAD_A(31, FB); CORNERS(S0, dvA, 33); DESC_LD(35, dvC);
  BLEND(S1, ldsB1); MFMA4(FA, ldsB0); BAR();
  // c=31 (k=1)
  LOAD_A(32, FA); CORNERS(S1, dvB, 34);
  BLEND(S2, ldsB0); MFMA4(FB, ldsB1); BAR();
  // c=32 (k=2)
  LOAD_A(33, FB); CORNERS(S2, dvC, 35);
  BLEND(S0, ldsB1); MFMA4(FA, ldsB0); BAR();
  // c=33 (k=3)
  LOAD_A(34, FA);
  BLEND(S1, ldsB0); MFMA4(FB, ldsB1); BAR();
  // c=34 (k=4)
  LOAD_A(35, FB);
  BLEND(S2, ldsB1); MFMA4(FA, ldsB0); BAR();
  // c=35 (k=5)
  MFMA4(FB, ldsB1);

  // ---- epilogue: ReLU + fp32 store ----
  const int lm4 = (l >> 4) << 2;
  float* ob = out + (size_t)(b * 256 + wid * 32) * 4096 + y * 64 + xh * 32;
#pragma unroll
  for (int r = 0; r < 4; ++r) {
    ob[(size_t)(lm4 + r) * 4096 + lm] = fmaxf(acc00[r], 0.f);
    ob[(size_t)(lm4 + r) * 4096 + 16 + lm] = fmaxf(acc01[r], 0.f);
    ob[(size_t)(16 + lm4 + r) * 4096 + lm] = fmaxf(acc10[r], 0.f);
    ob[(size_t)(16 + lm4 + r) * 4096 + 16 + lm] = fmaxf(acc11[r], 0.f);
  }
}

extern "C" void kernel_launch(void* const* d_in, const int* in_sizes, int n_in,
                              void* d_out, int out_size, void* d_ws, size_t ws_size,
                              hipStream_t stream) {
  const float* x     = (const float*)d_in[0];
  const float* shape = (const float*)d_in[1];
  const float* w_off = (const float*)d_in[2];
  const float* w_def = (const float*)d_in[3];
  float* out = (float*)d_out;
  char* ws = (char*)d_ws;

  char* desc          = ws;                                          // 9,437,184 B
  unsigned short* xt  = (unsigned short*)(ws + 9437184);             // 8,388,608 B
  unsigned short* wpk = (unsigned short*)(ws + 9437184 + 8388608);   // 1,179,648 B

  k_prep<<<1856, 256, 0, stream>>>(shape, w_off, x, w_def, desc, xt, wpk);
  k_deform_main<<<512, 512, 0, stream>>>(xt, wpk, desc, out);
}